// Round 2
// baseline (9766.850 us; speedup 1.0000x reference)
//
#include <hip/hip_runtime.h>
#include <hip/hip_cooperative_groups.h>

namespace cg = cooperative_groups;

typedef __attribute__((ext_vector_type(8))) short short8;
typedef __attribute__((ext_vector_type(4))) float f32x4;

#define OSTEP (256*1408)

// ---- ws layout (ushort elems from base) ----
#define OFF_WIH  ((size_t)0)
#define OFF_WHH  ((size_t)3145728)
#define OFF_WP1  ((size_t)6291456)
#define OFF_WQ1  ((size_t)7340032)
#define OFF_WP2  ((size_t)9437184)
#define OFF_WQ2  ((size_t)9568256)
#define OFF_WSA  ((size_t)9699328)
#define OFF_HBF0 ((size_t)9797632)
#define OFF_HBF1 ((size_t)10059776)
#define OFF_EBF  ((size_t)10321920)
#define OFF_P1E  ((size_t)10584064)
#define OFF_Q1E  ((size_t)10846208)
#define OFF_OBSB ((size_t)11108352)

__device__ __forceinline__ unsigned short f2bf(float f){
  union { float f; unsigned u; } v; v.f = f;
  unsigned u = v.u;
  u += 0x7fffu + ((u >> 16) & 1u);
  return (unsigned short)(u >> 16);
}
__device__ __forceinline__ unsigned long long pack4(float4 v){
  return (unsigned long long)f2bf(v.x) | ((unsigned long long)f2bf(v.y)<<16)
       | ((unsigned long long)f2bf(v.z)<<32) | ((unsigned long long)f2bf(v.w)<<48);
}
__device__ __forceinline__ float sigf(float x){ return 1.0f/(1.0f+__expf(-x)); }
__device__ __forceinline__ float tanhf_(float x){
  float e = __expf(-2.0f*fabsf(x));
  float t = (1.0f-e)/(1.0f+e);
  return x>=0.f ? t : -t;
}
__device__ __forceinline__ float eluf(float x){ return x>0.f ? x : __expf(x)-1.0f; }
__device__ __forceinline__ float softplusf(float x){ return x>20.f ? x : log1pf(__expf(x)); }
__device__ __forceinline__ short8 ld8(const unsigned short* p){ return *(const short8*)p; }
__device__ __forceinline__ short8 cvt8(const float* p){
  short8 r;
  #pragma unroll
  for(int i=0;i<8;i++) r[i]=(short)f2bf(p[i]);
  return r;
}
#define MFMA(a,b,c) __builtin_amdgcn_mfma_f32_16x16x32_bf16((a),(b),(c),0,0,0)

// e = elu([qst | act] @ W_sa^T + b_sa) for 16 rows starting at row0.
// sst[16][96] holds [qst(64) | act(32)] fp32. wave w covers cols w*256..+256.
__device__ __forceinline__ void e_gemm(int row0, int w, int lane,
    const float (*sst)[96], const unsigned short* wsab, const float* bsa,
    unsigned short* ebf){
  int l15 = lane&15, q8 = (lane>>4)*8, rr = (lane>>4)*4;
  short8 a0 = cvt8(&sst[l15][q8]);
  short8 a1 = cvt8(&sst[l15][32+q8]);
  short8 a2 = cvt8(&sst[l15][64+q8]);
  #pragma unroll 4
  for(int n=0;n<16;n++){
    int col = w*256 + n*16 + l15;
    const unsigned short* pb = wsab + (size_t)col*96 + q8;
    f32x4 c = {0.f,0.f,0.f,0.f};
    c = MFMA(a0, ld8(pb),    c);
    c = MFMA(a1, ld8(pb+32), c);
    c = MFMA(a2, ld8(pb+64), c);
    float bb = bsa[col];
    #pragma unroll
    for(int v=0;v<4;v++)
      ebf[(size_t)(row0+rr+v)*1024 + col] = f2bf(eluf(c[v]+bb));
  }
}

__global__ __launch_bounds__(256,1) void k_rssm(
    const float* __restrict__ obs, const float* __restrict__ act,
    const float* __restrict__ np_, const float* __restrict__ nq_,
    const float* __restrict__ wsa_f, const float* __restrict__ bsa,
    const float* __restrict__ wih_f, const float* __restrict__ bih,
    const float* __restrict__ whh_f, const float* __restrict__ bhh,
    const float* __restrict__ wp1_f, const float* __restrict__ bp1,
    const float* __restrict__ wp2_f, const float* __restrict__ bp2,
    const float* __restrict__ wq1_f, const float* __restrict__ bq1,
    const float* __restrict__ wq2_f, const float* __restrict__ bq2,
    float* __restrict__ out, unsigned short* __restrict__ wsb)
{
  cg::grid_group grid = cg::this_grid();
  const int p = blockIdx.x, tid = threadIdx.x;
  const int w = tid>>6, lane = tid&63;
  const int l15 = lane&15, q8 = (lane>>4)*8, rr = (lane>>4)*4;
  const int gtid = p*256 + tid;

  unsigned short* wihb = wsb + OFF_WIH;
  unsigned short* whhb = wsb + OFF_WHH;
  unsigned short* wp1b = wsb + OFF_WP1;
  unsigned short* wq1b = wsb + OFF_WQ1;
  unsigned short* wp2b = wsb + OFF_WP2;
  unsigned short* wq2b = wsb + OFF_WQ2;
  unsigned short* wsab = wsb + OFF_WSA;
  unsigned short* ebf  = wsb + OFF_EBF;
  unsigned short* p1e  = wsb + OFF_P1E;
  unsigned short* q1e  = wsb + OFF_Q1E;
  unsigned short* obsb = wsb + OFF_OBSB;

  __shared__ float sm[16][130];   // pm/qm tile (padded vs bank conflicts)
  __shared__ float sst[16][96];   // [qstoch | act] staging for e-GEMM

  // ---- phase -1: weight fp32->bf16 conversion + h init ----
  {
    const float* srcs[7] = {wih_f, whh_f, wp1_f, wq1_f, wp2_f, wq2_f, wsa_f};
    const size_t offs[7] = {OFF_WIH, OFF_WHH, OFF_WP1, OFF_WQ1, OFF_WP2, OFF_WQ2, OFF_WSA};
    const size_t cnts[7] = {3145728,3145728,1048576,2097152,131072,131072,98304};
    #pragma unroll 1
    for(int s=0;s<7;s++){
      const float4* src = (const float4*)srcs[s];
      unsigned long long* dst = (unsigned long long*)(wsb + offs[s]);
      size_t n4 = cnts[s] >> 2;
      for(size_t i=gtid; i<n4; i+=65536) dst[i] = pack4(src[i]);
    }
    unsigned long long* hz = (unsigned long long*)(wsb + OFF_HBF0);
    hz[gtid] = 0ull;  // 65536 * 4 ushorts = hbf0 fully zeroed
  }
  grid.sync();

  // ---- e_0: s0 = 0, act col 0 ----
  if(p < 16){
    int row0 = p*16;
    for(int i=tid;i<16*96;i+=256) (&sst[0][0])[i] = 0.f;
    __syncthreads();
    for(int i=tid;i<512;i+=256){ int r=i>>5, a2=i&31;
      sst[r][64+a2] = act[((size_t)(row0+r)*64 + 0)*32 + a2]; }
    __syncthreads();
    e_gemm(row0, w, lane, sst, wsab, bsa, ebf);
  }
  grid.sync();

  for(int t=0;t<63;t++){
    const unsigned short* hb  = (t&1) ? wsb+OFF_HBF1 : wsb+OFF_HBF0;
    unsigned short*       hbn = (t&1) ? wsb+OFF_HBF0 : wsb+OFF_HBF1;
    float* out_t = out + (size_t)t*OSTEP;

    // ======== phase 1: GRU (gi, gh, gates, h_new) ========
    {
      int j = p>>2, m = p&3;
      int row0 = m*64 + w*16;
      const unsigned short* pe = ebf + (size_t)(row0+l15)*1024 + q8;
      const unsigned short* ph = hb  + (size_t)(row0+l15)*1024 + q8;
      int d = j*16 + l15;
      const unsigned short* pwi = wihb + (size_t)d*1024 + q8;
      const unsigned short* pwh = whhb + (size_t)d*1024 + q8;
      f32x4 z4 = {0.f,0.f,0.f,0.f};
      f32x4 aIR=z4, aIZ=z4, aIA=z4, aHR=z4, aHZ=z4, aHA=z4;
      #pragma unroll 2
      for(int k=0;k<1024;k+=32){
        short8 ae = ld8(pe+k), ah = ld8(ph+k);
        aIR = MFMA(ae, ld8(pwi+k),         aIR);
        aIZ = MFMA(ae, ld8(pwi+1048576+k), aIZ);
        aIA = MFMA(ae, ld8(pwi+2097152+k), aIA);
        aHR = MFMA(ah, ld8(pwh+k),         aHR);
        aHZ = MFMA(ah, ld8(pwh+1048576+k), aHZ);
        aHA = MFMA(ah, ld8(pwh+2097152+k), aHA);
      }
      float bir=bih[d], biz=bih[1024+d], bia=bih[2048+d];
      float bhr=bhh[d], bhz=bhh[1024+d], bha=bhh[2048+d];
      #pragma unroll
      for(int v=0;v<4;v++){
        int b = row0 + rr + v;
        float r  = sigf(aIR[v]+bir + aHR[v]+bhr);
        float zz = sigf(aIZ[v]+biz + aHZ[v]+bhz);
        float nn = tanhf_(aIA[v]+bia + r*(aHA[v]+bha));
        float hold = (t==0) ? 0.f : out[(size_t)(t-1)*OSTEP + (size_t)b*1408 + d];
        float hnew = (1.f-zz)*nn + zz*hold;
        out_t[(size_t)b*1408 + d] = hnew;
        hbn[(size_t)b*1024 + d] = f2bf(hnew);
      }
      // obs[:, t+1] fp32 -> bf16 (one float4 per thread, 65536 total)
      int bo = gtid>>8, e4 = (gtid&255)*4;
      float4 v = *(const float4*)(obs + ((size_t)bo*64 + (t+1))*1024 + e4);
      *(unsigned long long*)(obsb + (size_t)bo*1024 + e4) = pack4(v);
    }
    grid.sync();

    // ======== phase 2: heads1 (p1 = elu(h@Wp1^T+b), q1 = elu([h,obs]@Wq1^T+b)) ========
    {
      int j = p>>2, m = p&3;
      int row0 = m*64 + w*16;
      const unsigned short* pa = hbn  + (size_t)(row0+l15)*1024 + q8;
      const unsigned short* po = obsb + (size_t)(row0+l15)*1024 + q8;
      int hc = j*16 + l15;
      const unsigned short* pbp = wp1b + (size_t)hc*1024 + q8;
      const unsigned short* pbq = wq1b + (size_t)hc*2048 + q8;
      f32x4 z4 = {0.f,0.f,0.f,0.f};
      f32x4 ap=z4, aq=z4, ao=z4;
      #pragma unroll 2
      for(int k=0;k<1024;k+=32){
        short8 a = ld8(pa+k), o = ld8(po+k);
        ap = MFMA(a, ld8(pbp+k),      ap);
        aq = MFMA(a, ld8(pbq+k),      aq);
        ao = MFMA(o, ld8(pbq+1024+k), ao);
      }
      float bp = bp1[hc], bq = bq1[hc];
      #pragma unroll
      for(int v=0;v<4;v++){
        int b = row0 + rr + v;
        p1e[(size_t)b*1024 + hc] = f2bf(eluf(ap[v]+bp));
        q1e[(size_t)b*1024 + hc] = f2bf(eluf(aq[v]+ao[v]+bq));
      }
    }
    grid.sync();

    // ======== phase 3: heads2 + sample + out-writes + e_next (blocks 0..31) ========
    if(p < 32){
      bool isQ = (p < 16);
      int row0 = (p&15)*16;
      const unsigned short* A  = isQ ? q1e : p1e;
      const unsigned short* W2 = isQ ? wq2b : wp2b;
      const float* b2 = isQ ? bq2 : bp2;
      const unsigned short* pa  = A  + (size_t)(row0+l15)*1024 + q8;
      const unsigned short* pb0 = W2 + (size_t)(w*32+l15)*1024 + q8;
      const unsigned short* pb1 = pb0 + (size_t)16*1024;
      f32x4 c0 = {0.f,0.f,0.f,0.f}, c1 = c0;
      #pragma unroll 2
      for(int k=0;k<1024;k+=32){
        short8 a = ld8(pa+k);
        c0 = MFMA(a, ld8(pb0+k), c0);
        c1 = MFMA(a, ld8(pb1+k), c1);
      }
      int cb = w*32 + l15;
      #pragma unroll
      for(int v=0;v<4;v++){
        sm[rr+v][cb]    = c0[v] + b2[cb];
        sm[rr+v][cb+16] = c1[v] + b2[cb+16];
      }
      __syncthreads();
      const float* noise = isQ ? nq_ : np_;
      int obase = isQ ? 1216 : 1024;
      for(int i=tid;i<1024;i+=256){
        int r=i>>6, s=i&63; int b=row0+r;
        float mean = sm[r][s];
        float stdv = softplusf(sm[r][64+s]) + 0.1f;
        float samp = mean + stdv * noise[((size_t)t*256 + b)*64 + s];
        float* o = out_t + (size_t)b*1408 + obase;
        o[s]=mean; o[64+s]=stdv; o[128+s]=samp;
        if(isQ) sst[r][s] = samp;
      }
      if(isQ){
        for(int i=tid;i<512;i+=256){ int r=i>>5, a2=i&31;
          sst[r][64+a2] = act[((size_t)(row0+r)*64 + (t+1))*32 + a2]; }
      }
      __syncthreads();
      if(isQ) e_gemm(row0, w, lane, sst, wsab, bsa, ebf);
    }
    grid.sync();
  }
}

extern "C" void kernel_launch(void* const* d_in, const int* in_sizes, int n_in,
                              void* d_out, int out_size, void* d_ws, size_t ws_size,
                              hipStream_t stream) {
  const float* obs = (const float*)d_in[0];
  const float* act = (const float*)d_in[1];
  const float* np_ = (const float*)d_in[2];
  const float* nq_ = (const float*)d_in[3];
  const float* wsa = (const float*)d_in[4];
  const float* bsa = (const float*)d_in[5];
  const float* wih = (const float*)d_in[6];
  const float* bih = (const float*)d_in[7];
  const float* whh = (const float*)d_in[8];
  const float* bhh = (const float*)d_in[9];
  const float* wp1 = (const float*)d_in[10];
  const float* bp1 = (const float*)d_in[11];
  const float* wp2 = (const float*)d_in[12];
  const float* bp2 = (const float*)d_in[13];
  const float* wq1 = (const float*)d_in[14];
  const float* bq1 = (const float*)d_in[15];
  const float* wq2 = (const float*)d_in[16];
  const float* bq2 = (const float*)d_in[17];
  float* out = (float*)d_out;
  unsigned short* wsb = (unsigned short*)d_ws;

  void* args[] = {
    (void*)&obs, (void*)&act, (void*)&np_, (void*)&nq_,
    (void*)&wsa, (void*)&bsa, (void*)&wih, (void*)&bih,
    (void*)&whh, (void*)&bhh, (void*)&wp1, (void*)&bp1,
    (void*)&wp2, (void*)&bp2, (void*)&wq1, (void*)&bq1,
    (void*)&wq2, (void*)&bq2, (void*)&out, (void*)&wsb
  };
  hipLaunchCooperativeKernel((const void*)k_rssm, dim3(256), dim3(256), args, 0, stream);
}